// Round 3
// baseline (134.654 us; speedup 1.0000x reference)
//
#include <hip/hip_runtime.h>
#include <math.h>

#define F 256
#define E 256
#define S 32
#define CH 4

// ---------------------------------------------------------------------------
// Kernel A: M = Wq @ Wk^T  [F][F],  c = bq @ Wk^T  [F]
// grid = F+1 blocks (block F computes c), 256 threads.
// ---------------------------------------------------------------------------
__global__ __launch_bounds__(256) void prep_M(const float* __restrict__ Wq,
                                              const float* __restrict__ bq,
                                              const float* __restrict__ Wk,
                                              float* __restrict__ M,
                                              float* __restrict__ c) {
    const int i = blockIdx.x;
    const int j = threadIdx.x;
    __shared__ float row[E];
    row[j] = (i < F) ? Wq[i * E + j] : bq[j];
    __syncthreads();
    float acc = 0.f;
#pragma unroll 8
    for (int e = 0; e < E; e += 4) {
        float4 w = *reinterpret_cast<const float4*>(&Wk[j * E + e]);
        acc += row[e] * w.x + row[e + 1] * w.y + row[e + 2] * w.z + row[e + 3] * w.w;
    }
    if (i < F) M[i * F + j] = acc;
    else       c[j] = acc;
}

// ---------------------------------------------------------------------------
// Kernel B/D: out[r][:] = X[idx ? idx[r] : r][:] @ W + bias   (f32, K=N=256)
// 64x64 tile per block, 256 threads, 4x4 micro-tile per thread.
// ---------------------------------------------------------------------------
__global__ __launch_bounds__(256) void gemm_bias(const float* __restrict__ X,
                                                 const int* __restrict__ idx,
                                                 const float* __restrict__ W,
                                                 const float* __restrict__ bias,
                                                 float* __restrict__ out,
                                                 int rows) {
    __shared__ float xsT[64][68];   // [k][r], stride 68 keeps 16B alignment + spreads banks
    __shared__ float wt[64][64];    // [k][j_local]
    const int tid = threadIdx.x;
    const int tx = tid & 15, ty = tid >> 4;
    const int bn = blockIdx.x, bm = blockIdx.y;
    const int jb = bn * 64 + tx * 4;
    float acc[4][4] = {{0.f}};

    for (int k0 = 0; k0 < F; k0 += 64) {
#pragma unroll
        for (int p = 0; p < 4; ++p) {
            // stage X tile (transposed into LDS)
            const int lr = p * 16 + ty;       // local row 0..63
            const int lk = tx * 4;            // local k   0..60
            const int gr = bm * 64 + lr;
            const int grc = gr < rows ? gr : rows - 1;
            const long grow = idx ? (long)idx[grc] : (long)grc;
            float4 v = *reinterpret_cast<const float4*>(&X[grow * F + k0 + lk]);
            xsT[lk + 0][lr] = v.x; xsT[lk + 1][lr] = v.y;
            xsT[lk + 2][lr] = v.z; xsT[lk + 3][lr] = v.w;
            // stage W tile
            const int wk = p * 16 + ty;
            float4 wv = *reinterpret_cast<const float4*>(&W[(size_t)(k0 + wk) * E + bn * 64 + tx * 4]);
            *reinterpret_cast<float4*>(&wt[wk][tx * 4]) = wv;
        }
        __syncthreads();
#pragma unroll 16
        for (int k = 0; k < 64; ++k) {
            float4 a = *reinterpret_cast<const float4*>(&xsT[k][ty * 4]);
            float4 b = *reinterpret_cast<const float4*>(&wt[k][tx * 4]);
            acc[0][0] += a.x * b.x; acc[0][1] += a.x * b.y; acc[0][2] += a.x * b.z; acc[0][3] += a.x * b.w;
            acc[1][0] += a.y * b.x; acc[1][1] += a.y * b.y; acc[1][2] += a.y * b.z; acc[1][3] += a.y * b.w;
            acc[2][0] += a.z * b.x; acc[2][1] += a.z * b.y; acc[2][2] += a.z * b.z; acc[2][3] += a.z * b.w;
            acc[3][0] += a.w * b.x; acc[3][1] += a.w * b.y; acc[3][2] += a.w * b.z; acc[3][3] += a.w * b.w;
        }
        __syncthreads();
    }

    const float4 bb = *reinterpret_cast<const float4*>(&bias[jb]);
#pragma unroll
    for (int v = 0; v < 4; ++v) {
        const int r = bm * 64 + ty * 4 + v;
        if (r < rows) {
            float4 o;
            o.x = acc[v][0] + bb.x; o.y = acc[v][1] + bb.y;
            o.z = acc[v][2] + bb.z; o.w = acc[v][3] + bb.w;
            *reinterpret_cast<float4*>(&out[(size_t)r * E + jb]) = o;
        }
    }
}

// ---------------------------------------------------------------------------
// Kernel C v3: one wave per node, SINGLE-PASS online softmax, rows die
// immediately after use -> low VGPR -> high occupancy. 4-row chunks,
// double-buffered with static indexing (runtime-indexed reg arrays would
// spill to scratch). Loads for chunk k+1 are in flight while chunk k is
// dotted/folded. The max-update branch is wave-uniform: after the full
// xor-butterfly every lane holds a bit-identical score.
// qtm holds q-tilde on entry, overwritten with m = sum_s attn_s * row_s.
// ---------------------------------------------------------------------------
__device__ __forceinline__ void ld_chunk(float4* d, int idxv, int s0,
                                         const float* __restrict__ t, int lane) {
#pragma unroll
    for (int j = 0; j < CH; ++j) {
        const int nid = __builtin_amdgcn_readlane(idxv, s0 + j);
        d[j] = *reinterpret_cast<const float4*>(&t[(size_t)nid * F + lane * 4]);
    }
}

__device__ __forceinline__ void proc_chunk(const float4* v, const float4 qv,
                                           float& m, float& l, float4& acc) {
#pragma unroll
    for (int j = 0; j < CH; ++j) {
        float p = v[j].x * qv.x + v[j].y * qv.y + v[j].z * qv.z + v[j].w * qv.w;
#pragma unroll
        for (int off = 32; off; off >>= 1) p += __shfl_xor(p, off);
        if (p <= m) {                       // common path: max unchanged
            const float w = __expf(p - m);
            l += w;
            acc.x += w * v[j].x; acc.y += w * v[j].y;
            acc.z += w * v[j].z; acc.w += w * v[j].w;
        } else {                            // rescale path (~log S times)
            const float c = __expf(m - p);  // m=-inf first row -> c=0
            l = l * c + 1.f;
            acc.x = acc.x * c + v[j].x; acc.y = acc.y * c + v[j].y;
            acc.z = acc.z * c + v[j].z; acc.w = acc.w * c + v[j].w;
            m = p;
        }
    }
}

__global__ __launch_bounds__(256) void attn_gather(const int* __restrict__ neigh_idx,
                                                   const float* __restrict__ id2feat,
                                                   float* __restrict__ qtm,
                                                   int B) {
    const int node = blockIdx.x * 4 + (threadIdx.x >> 6);
    const int lane = threadIdx.x & 63;
    if (node >= B) return;

    // one coalesced load: lane l holds neigh id (l & 31)
    const int idxv = neigh_idx[node * S + (lane & (S - 1))];
    const float4 qv = *reinterpret_cast<const float4*>(&qtm[(size_t)node * F + lane * 4]);

    float m = -INFINITY, l = 0.f;
    float4 acc = make_float4(0.f, 0.f, 0.f, 0.f);

    float4 va[CH], vb[CH];
    ld_chunk(va, idxv, 0, id2feat, lane);
    ld_chunk(vb, idxv, 4, id2feat, lane);
    proc_chunk(va, qv, m, l, acc);
    ld_chunk(va, idxv, 8, id2feat, lane);
    proc_chunk(vb, qv, m, l, acc);
    ld_chunk(vb, idxv, 12, id2feat, lane);
    proc_chunk(va, qv, m, l, acc);
    ld_chunk(va, idxv, 16, id2feat, lane);
    proc_chunk(vb, qv, m, l, acc);
    ld_chunk(vb, idxv, 20, id2feat, lane);
    proc_chunk(va, qv, m, l, acc);
    ld_chunk(va, idxv, 24, id2feat, lane);
    proc_chunk(vb, qv, m, l, acc);
    ld_chunk(vb, idxv, 28, id2feat, lane);
    proc_chunk(va, qv, m, l, acc);
    proc_chunk(vb, qv, m, l, acc);

    const float inv = 1.0f / l;
    float4 o;
    o.x = acc.x * inv; o.y = acc.y * inv; o.z = acc.z * inv; o.w = acc.w * inv;
    *reinterpret_cast<float4*>(&qtm[(size_t)node * F + lane * 4]) = o;
}

// ---------------------------------------------------------------------------
extern "C" void kernel_launch(void* const* d_in, const int* in_sizes, int n_in,
                              void* d_out, int out_size, void* d_ws, size_t ws_size,
                              hipStream_t stream) {
    const int*   nodes   = (const int*)d_in[0];
    const int*   neigh   = (const int*)d_in[1];
    const float* id2feat = (const float*)d_in[2];
    const float* Wq      = (const float*)d_in[3];
    const float* bq      = (const float*)d_in[4];
    const float* Wk      = (const float*)d_in[5];
    // d_in[6] = bk is unused: a per-row constant in the logits is
    // softmax-invariant (self column is masked, so it shifts ALL live logits).
    const float* Wv      = (const float*)d_in[7];
    const float* bv      = (const float*)d_in[8];
    float* out = (float*)d_out;
    const int B = in_sizes[0];

    float* Mbuf = (float*)d_ws;          // [F][F]
    float* cbuf = Mbuf + F * F;          // [F]
    float* qtm  = cbuf + F;              // [B][F]: q-tilde, then m (reused)

    // A: M = Wq Wk^T, c = bq Wk^T
    prep_M<<<dim3(F + 1), dim3(256), 0, stream>>>(Wq, bq, Wk, Mbuf, cbuf);
    // B: q~ = gather(id2feat, nodes) @ M + c
    gemm_bias<<<dim3(4, (B + 63) / 64), dim3(256), 0, stream>>>(id2feat, nodes, Mbuf, cbuf, qtm, B);
    // C: scores -> softmax -> m (in place over qtm), one wave per node
    attn_gather<<<dim3((B + 3) / 4), dim3(256), 0, stream>>>(neigh, id2feat, qtm, B);
    // D: out = m @ Wv + bv
    gemm_bias<<<dim3(4, (B + 63) / 64), dim3(256), 0, stream>>>(qtm, nullptr, Wv, bv, out, B);
}

// Round 4
// 122.535 us; speedup vs baseline: 1.0989x; 1.0989x over previous
//
#include <hip/hip_runtime.h>
#include <math.h>

#define F 256
#define E 256
#define S 32
#define CH 4
#define LDK 40   // padded LDS k-stride in bf16 elems (80 B -> 2-way-max bank aliasing)

typedef __attribute__((ext_vector_type(8))) short short8;
typedef __attribute__((ext_vector_type(4))) float f32x4;

__device__ __forceinline__ ushort f2bf(float x) {
    uint u = __float_as_uint(x);
    uint r = (u + 0x7fffu + ((u >> 16) & 1u)) >> 16;
    return (ushort)r;
}
__device__ __forceinline__ float bf2f(ushort h) {
    return __uint_as_float(((uint)h) << 16);
}

// ---------------------------------------------------------------------------
// prep_all: blocks 0..255:  MT[j][i] = (Wq Wk^T)[i][j] = Wk_j . Wq_i  -> hi/lo
//                           c[j] = Wk_j . bq
//           blocks 256..511: WvT[j][k] = Wv[k][j] -> hi/lo
// ---------------------------------------------------------------------------
__global__ __launch_bounds__(256) void prep_all(const float* __restrict__ Wq,
                                                const float* __restrict__ bq,
                                                const float* __restrict__ Wk,
                                                const float* __restrict__ Wv,
                                                ushort* __restrict__ MT_hi,
                                                ushort* __restrict__ MT_lo,
                                                ushort* __restrict__ WvT_hi,
                                                ushort* __restrict__ WvT_lo,
                                                float* __restrict__ c) {
    const int t = threadIdx.x;
    if (blockIdx.x < 256) {
        const int j = blockIdx.x;
        __shared__ float wkj[F];
        wkj[t] = Wk[j * F + t];
        __syncthreads();
        float acc = 0.f;
#pragma unroll 8
        for (int e = 0; e < F; e += 4) {
            float4 wq = *reinterpret_cast<const float4*>(&Wq[t * E + e]);
            acc += wkj[e] * wq.x + wkj[e + 1] * wq.y + wkj[e + 2] * wq.z + wkj[e + 3] * wq.w;
        }
        const ushort hi = f2bf(acc);
        MT_hi[j * F + t] = hi;
        MT_lo[j * F + t] = f2bf(acc - bf2f(hi));
        if (t == 0) {
            float s = 0.f;
            for (int e = 0; e < F; ++e) s += wkj[e] * bq[e];
            c[j] = s;
        }
    } else {
        const int j = blockIdx.x - 256;
        const float v = Wv[t * E + j];
        const ushort hi = f2bf(v);
        WvT_hi[j * F + t] = hi;
        WvT_lo[j * F + t] = f2bf(v - bf2f(hi));
    }
}

// ---------------------------------------------------------------------------
// mfma_gemm: out[r][:] = X[idx ? idx[r] : r][:] @ B + bias, via bf16x3 split
// (Ahi*Bhi + Ahi*Blo + Alo*Bhi), B given pre-transposed/split as BT[col][k].
// Tile: BM=64, BN=256 (full N, X read once), BK=32. 256 thr = 4 waves (2Mx2N),
// each wave 32x128 via 2x8 16x16x32 fragments, f32 accumulate.
// ---------------------------------------------------------------------------
__global__ __launch_bounds__(256) void mfma_gemm(const float* __restrict__ X,
                                                 const int* __restrict__ idx,
                                                 const ushort* __restrict__ BTh,
                                                 const ushort* __restrict__ BTl,
                                                 const float* __restrict__ bias,
                                                 float* __restrict__ out,
                                                 int rows) {
    __shared__ ushort Ah[64][LDK], Al[64][LDK];
    __shared__ ushort Bh[256][LDK], Bl[256][LDK];

    const int tid = threadIdx.x;
    const int lane = tid & 63, wave = tid >> 6;
    const int wm = wave >> 1, wn = wave & 1;
    const int fr = lane & 15, fk = lane >> 4;
    const int row0 = blockIdx.x * 64;

    // A staging coords: thread t stages row t>>2, k-octet (t&3)*8
    const int arL = tid >> 2;
    const int akL = (tid & 3) * 8;
    const int ar = row0 + arL;
    const int arc = ar < rows ? ar : rows - 1;
    const long arow = idx ? (long)idx[arc] : (long)arc;
    const float* aptr = X + arow * (long)F + akL;

    // B staging: thread t owns col t (reads BT row t)
    const ushort* bhp = BTh + (size_t)tid * F;
    const ushort* blp = BTl + (size_t)tid * F;

    f32x4 acc[2][8];
#pragma unroll
    for (int m = 0; m < 2; ++m)
#pragma unroll
        for (int n = 0; n < 8; ++n) acc[m][n] = (f32x4){0.f, 0.f, 0.f, 0.f};

    for (int k0 = 0; k0 < F; k0 += 32) {
        // global loads first (latency overlap with the barrier)
        const float4 v0 = *reinterpret_cast<const float4*>(&aptr[k0]);
        const float4 v1 = *reinterpret_cast<const float4*>(&aptr[k0 + 4]);
        const uint4 bh0 = *reinterpret_cast<const uint4*>(&bhp[k0]);
        const uint4 bh1 = *reinterpret_cast<const uint4*>(&bhp[k0 + 8]);
        const uint4 bh2 = *reinterpret_cast<const uint4*>(&bhp[k0 + 16]);
        const uint4 bh3 = *reinterpret_cast<const uint4*>(&bhp[k0 + 24]);
        const uint4 bl0 = *reinterpret_cast<const uint4*>(&blp[k0]);
        const uint4 bl1 = *reinterpret_cast<const uint4*>(&blp[k0 + 8]);
        const uint4 bl2 = *reinterpret_cast<const uint4*>(&blp[k0 + 16]);
        const uint4 bl3 = *reinterpret_cast<const uint4*>(&blp[k0 + 24]);

        // split A to hi/lo bf16
        const float xv[8] = {v0.x, v0.y, v0.z, v0.w, v1.x, v1.y, v1.z, v1.w};
        ushort h[8], l[8];
#pragma unroll
        for (int jj = 0; jj < 8; ++jj) {
            h[jj] = f2bf(xv[jj]);
            l[jj] = f2bf(xv[jj] - bf2f(h[jj]));
        }
        uint4 ph, pl;
        ph.x = (uint)h[0] | ((uint)h[1] << 16); ph.y = (uint)h[2] | ((uint)h[3] << 16);
        ph.z = (uint)h[4] | ((uint)h[5] << 16); ph.w = (uint)h[6] | ((uint)h[7] << 16);
        pl.x = (uint)l[0] | ((uint)l[1] << 16); pl.y = (uint)l[2] | ((uint)l[3] << 16);
        pl.z = (uint)l[4] | ((uint)l[5] << 16); pl.w = (uint)l[6] | ((uint)l[7] << 16);

        __syncthreads();   // previous iteration's fragment reads complete
        *reinterpret_cast<uint4*>(&Ah[arL][akL]) = ph;
        *reinterpret_cast<uint4*>(&Al[arL][akL]) = pl;
        *reinterpret_cast<uint4*>(&Bh[tid][0])  = bh0;
        *reinterpret_cast<uint4*>(&Bh[tid][8])  = bh1;
        *reinterpret_cast<uint4*>(&Bh[tid][16]) = bh2;
        *reinterpret_cast<uint4*>(&Bh[tid][24]) = bh3;
        *reinterpret_cast<uint4*>(&Bl[tid][0])  = bl0;
        *reinterpret_cast<uint4*>(&Bl[tid][8])  = bl1;
        *reinterpret_cast<uint4*>(&Bl[tid][16]) = bl2;
        *reinterpret_cast<uint4*>(&Bl[tid][24]) = bl3;
        __syncthreads();

        // fragments: A rows wm*32 + m*16 + fr, k-octet fk*8 (contiguous 8)
        const short8 a_h0 = *reinterpret_cast<const short8*>(&Ah[wm * 32 + fr][fk * 8]);
        const short8 a_l0 = *reinterpret_cast<const short8*>(&Al[wm * 32 + fr][fk * 8]);
        const short8 a_h1 = *reinterpret_cast<const short8*>(&Ah[wm * 32 + 16 + fr][fk * 8]);
        const short8 a_l1 = *reinterpret_cast<const short8*>(&Al[wm * 32 + 16 + fr][fk * 8]);
#pragma unroll
        for (int n = 0; n < 8; ++n) {
            const short8 b_h = *reinterpret_cast<const short8*>(&Bh[wn * 128 + n * 16 + fr][fk * 8]);
            const short8 b_l = *reinterpret_cast<const short8*>(&Bl[wn * 128 + n * 16 + fr][fk * 8]);
            acc[0][n] = __builtin_amdgcn_mfma_f32_16x16x32_bf16(a_h0, b_h, acc[0][n], 0, 0, 0);
            acc[0][n] = __builtin_amdgcn_mfma_f32_16x16x32_bf16(a_h0, b_l, acc[0][n], 0, 0, 0);
            acc[0][n] = __builtin_amdgcn_mfma_f32_16x16x32_bf16(a_l0, b_h, acc[0][n], 0, 0, 0);
            acc[1][n] = __builtin_amdgcn_mfma_f32_16x16x32_bf16(a_h1, b_h, acc[1][n], 0, 0, 0);
            acc[1][n] = __builtin_amdgcn_mfma_f32_16x16x32_bf16(a_h1, b_l, acc[1][n], 0, 0, 0);
            acc[1][n] = __builtin_amdgcn_mfma_f32_16x16x32_bf16(a_l1, b_h, acc[1][n], 0, 0, 0);
        }
    }

    // epilogue: C/D map col=lane&15, row=(lane>>4)*4+reg  [m89-verified]
#pragma unroll
    for (int n = 0; n < 8; ++n) {
        const int col = wn * 128 + n * 16 + fr;
        const float bb = bias[col];
#pragma unroll
        for (int m = 0; m < 2; ++m) {
#pragma unroll
            for (int r = 0; r < 4; ++r) {
                const int orow = row0 + wm * 32 + m * 16 + fk * 4 + r;
                if (orow < rows)
                    out[(size_t)orow * E + col] = acc[m][n][r] + bb;
            }
        }
    }
}

// ---------------------------------------------------------------------------
// Kernel C (unchanged, at the random-gather memory wall): one wave per node,
// single-pass online softmax, 4-row double-buffered chunks.
// ---------------------------------------------------------------------------
__device__ __forceinline__ void ld_chunk(float4* d, int idxv, int s0,
                                         const float* __restrict__ t, int lane) {
#pragma unroll
    for (int j = 0; j < CH; ++j) {
        const int nid = __builtin_amdgcn_readlane(idxv, s0 + j);
        d[j] = *reinterpret_cast<const float4*>(&t[(size_t)nid * F + lane * 4]);
    }
}

__device__ __forceinline__ void proc_chunk(const float4* v, const float4 qv,
                                           float& m, float& l, float4& acc) {
#pragma unroll
    for (int j = 0; j < CH; ++j) {
        float p = v[j].x * qv.x + v[j].y * qv.y + v[j].z * qv.z + v[j].w * qv.w;
#pragma unroll
        for (int off = 32; off; off >>= 1) p += __shfl_xor(p, off);
        if (p <= m) {
            const float w = __expf(p - m);
            l += w;
            acc.x += w * v[j].x; acc.y += w * v[j].y;
            acc.z += w * v[j].z; acc.w += w * v[j].w;
        } else {
            const float c = __expf(m - p);
            l = l * c + 1.f;
            acc.x = acc.x * c + v[j].x; acc.y = acc.y * c + v[j].y;
            acc.z = acc.z * c + v[j].z; acc.w = acc.w * c + v[j].w;
            m = p;
        }
    }
}

__global__ __launch_bounds__(256) void attn_gather(const int* __restrict__ neigh_idx,
                                                   const float* __restrict__ id2feat,
                                                   float* __restrict__ qtm,
                                                   int B) {
    const int node = blockIdx.x * 4 + (threadIdx.x >> 6);
    const int lane = threadIdx.x & 63;
    if (node >= B) return;

    const int idxv = neigh_idx[node * S + (lane & (S - 1))];
    const float4 qv = *reinterpret_cast<const float4*>(&qtm[(size_t)node * F + lane * 4]);

    float m = -INFINITY, l = 0.f;
    float4 acc = make_float4(0.f, 0.f, 0.f, 0.f);

    float4 va[CH], vb[CH];
    ld_chunk(va, idxv, 0, id2feat, lane);
    ld_chunk(vb, idxv, 4, id2feat, lane);
    proc_chunk(va, qv, m, l, acc);
    ld_chunk(va, idxv, 8, id2feat, lane);
    proc_chunk(vb, qv, m, l, acc);
    ld_chunk(vb, idxv, 12, id2feat, lane);
    proc_chunk(va, qv, m, l, acc);
    ld_chunk(va, idxv, 16, id2feat, lane);
    proc_chunk(vb, qv, m, l, acc);
    ld_chunk(vb, idxv, 20, id2feat, lane);
    proc_chunk(va, qv, m, l, acc);
    ld_chunk(va, idxv, 24, id2feat, lane);
    proc_chunk(vb, qv, m, l, acc);
    ld_chunk(vb, idxv, 28, id2feat, lane);
    proc_chunk(va, qv, m, l, acc);
    proc_chunk(vb, qv, m, l, acc);

    const float inv = 1.0f / l;
    float4 o;
    o.x = acc.x * inv; o.y = acc.y * inv; o.z = acc.z * inv; o.w = acc.w * inv;
    *reinterpret_cast<float4*>(&qtm[(size_t)node * F + lane * 4]) = o;
}

// ---------------------------------------------------------------------------
extern "C" void kernel_launch(void* const* d_in, const int* in_sizes, int n_in,
                              void* d_out, int out_size, void* d_ws, size_t ws_size,
                              hipStream_t stream) {
    const int*   nodes   = (const int*)d_in[0];
    const int*   neigh   = (const int*)d_in[1];
    const float* id2feat = (const float*)d_in[2];
    const float* Wq      = (const float*)d_in[3];
    const float* bq      = (const float*)d_in[4];
    const float* Wk      = (const float*)d_in[5];
    // d_in[6] = bk unused: softmax-invariant (self column masked).
    const float* Wv      = (const float*)d_in[7];
    const float* bv      = (const float*)d_in[8];
    float* out = (float*)d_out;
    const int B = in_sizes[0];

    ushort* MT_hi  = (ushort*)d_ws;          // 256*256 = 65536 each
    ushort* MT_lo  = MT_hi + 65536;
    ushort* WvT_hi = MT_lo + 65536;
    ushort* WvT_lo = WvT_hi + 65536;
    float*  cbuf   = (float*)(WvT_lo + 65536);
    float*  qtm    = cbuf + 256;             // [B][F]: q-tilde, then m (reused)

    // prep: MT = (Wq Wk^T)^T split hi/lo, c = bq Wk^T, WvT = Wv^T split hi/lo
    prep_all<<<dim3(512), dim3(256), 0, stream>>>(Wq, bq, Wk, Wv,
                                                  MT_hi, MT_lo, WvT_hi, WvT_lo, cbuf);
    // B: q~ = gather(id2feat, nodes) @ M + c   (bf16x3 MFMA)
    mfma_gemm<<<dim3((B + 63) / 64), dim3(256), 0, stream>>>(id2feat, nodes,
                                                             MT_hi, MT_lo, cbuf, qtm, B);
    // C: scores -> softmax -> m (in place over qtm), one wave per node
    attn_gather<<<dim3((B + 3) / 4), dim3(256), 0, stream>>>(neigh, id2feat, qtm, B);
    // D: out = m @ Wv + bv   (bf16x3 MFMA)
    mfma_gemm<<<dim3((B + 63) / 64), dim3(256), 0, stream>>>(qtm, nullptr,
                                                             WvT_hi, WvT_lo, bv, out, B);
}